// Round 1
// baseline (1053.275 us; speedup 1.0000x reference)
//
#include <hip/hip_runtime.h>
#include <hip/hip_bf16.h>

#define B_ 2
#define T_ 2048
#define H_ 12
#define E_ 64
#define M_ 256
#define BLK 64
#define NBLK 32          // T_/BLK

constexpr float DN = 0.35355339059327373f;        // sqrt(1/sqrt(E)) = sqrt(0.125)
constexpr float HALF_LOG_M = 2.7725887222397811f; // 0.5*ln(256)
constexpr float NEGF = -1e30f;

// ---- monotonic float<->uint mapping for atomicMax on floats ----
__device__ __forceinline__ unsigned fkey(float f) {
  unsigned u = __float_as_uint(f);
  return (u & 0x80000000u) ? ~u : (u | 0x80000000u);
}
__device__ __forceinline__ float unfkey(unsigned k) {
  return (k & 0x80000000u) ? __uint_as_float(k & 0x7fffffffu) : __uint_as_float(~k);
}
// unpack 2 bf16 (packed in a u32, little-endian) to floats
__device__ __forceinline__ void bf2(unsigned u, float& a, float& b) {
  a = __uint_as_float(u << 16);
  b = __uint_as_float(u & 0xffff0000u);
}

// ---------------- workspace layout (bytes) ----------------
// 0        : s_k_bits   uint [24]
// 256      : kp_sum     f32  [24*256]
// 24832    : kv         f32  [24*256*64]
// 1597696  : q_log_scale f32 [24*2048]
// 1794304  : q_prime    bf16 [24*2048*256]
// 26960128 : k_prime    bf16 [24*2048*256]
// total ~52.2 MB

__global__ void init_ws(unsigned* __restrict__ skb, float* __restrict__ kpsum,
                        float* __restrict__ kv) {
  int i = blockIdx.x * blockDim.x + threadIdx.x;
  int stride = gridDim.x * blockDim.x;
  if (i < B_ * H_) skb[i] = 0u;  // below fkey(-inf)=0x007FFFFF
  for (int j = i; j < B_ * H_ * M_; j += stride) kpsum[j] = 0.f;
  for (int j = i; j < B_ * H_ * M_ * E_; j += stride) kv[j] = 0.f;
}

// k_dash pass. WRITE=false: reduce global max of k_shift -> skb.
// WRITE=true : k_prime = exp(k_shift - s_k) -> bf16.
template <bool WRITE>
__global__ __launch_bounds__(256) void kdash_kernel(
    const float* __restrict__ key, const float* __restrict__ proj,
    unsigned* __restrict__ skb, __hip_bfloat16* __restrict__ k_prime) {
  __shared__ float projT[E_][M_ + 1];  // [e][m]
  __shared__ float ks[BLK][E_ + 1];
  __shared__ float kd[BLK];
  __shared__ float red[4];

  const int blk = blockIdx.x;
  const int nb = blk & (NBLK - 1);
  const int bh = blk >> 5;
  const int b = bh / H_, h = bh % H_;
  const int t0 = nb * BLK;
  const int t = threadIdx.x;

  for (int idx = t; idx < M_ * E_; idx += 256)
    projT[idx & 63][idx >> 6] = proj[idx];
  for (int idx = t; idx < BLK * E_; idx += 256) {
    int i = idx >> 6, e = idx & 63;
    ks[i][e] = DN * key[(((size_t)b * T_ + t0 + i) * H_ + h) * E_ + e];
  }
  __syncthreads();
  if (t < BLK) {
    float s = 0.f;
#pragma unroll
    for (int e = 0; e < E_; e++) { float v = ks[t][e]; s += v * v; }
    kd[t] = 0.5f * s;
  }
  __syncthreads();

  float skval = 0.f;
  if (WRITE) skval = unfkey(skb[bh]);

  const int m = t;
  float lmax = -3.4e38f;
  for (int g = 0; g < 4; g++) {
    float acc[16];
#pragma unroll
    for (int r = 0; r < 16; r++) acc[r] = 0.f;
    for (int e = 0; e < E_; e++) {
      float pm = projT[e][m];
#pragma unroll
      for (int r = 0; r < 16; r++) acc[r] += ks[g * 16 + r][e] * pm;
    }
#pragma unroll
    for (int r = 0; r < 16; r++) {
      float shift = acc[r] - kd[g * 16 + r];
      if (WRITE) {
        float kp = __expf(shift - skval);
        k_prime[((size_t)bh * T_ + t0 + g * 16 + r) * M_ + m] = __float2bfloat16(kp);
      } else {
        lmax = fmaxf(lmax, shift);
      }
    }
  }
  if (!WRITE) {
#pragma unroll
    for (int off = 32; off > 0; off >>= 1)
      lmax = fmaxf(lmax, __shfl_xor(lmax, off));
    if ((t & 63) == 0) red[t >> 6] = lmax;
    __syncthreads();
    if (t == 0) {
      float mm = fmaxf(fmaxf(red[0], red[1]), fmaxf(red[2], red[3]));
      atomicMax(skb + bh, fkey(mm));
    }
  }
}

// q_dash -> per-row max -> q_prime (bf16), q_log_scale (f32)
__global__ __launch_bounds__(256) void qdash_kernel(
    const float* __restrict__ query, const float* __restrict__ proj,
    float* __restrict__ qls, __hip_bfloat16* __restrict__ q_prime) {
  __shared__ float projT[E_][M_ + 1];
  __shared__ float qsm[BLK][E_ + 1];
  __shared__ float qd[BLK];
  __shared__ float red[4][16];
  __shared__ float smax[16];

  const int blk = blockIdx.x;
  const int nb = blk & (NBLK - 1);
  const int bh = blk >> 5;
  const int b = bh / H_, h = bh % H_;
  const int t0 = nb * BLK;
  const int t = threadIdx.x;

  for (int idx = t; idx < M_ * E_; idx += 256)
    projT[idx & 63][idx >> 6] = proj[idx];
  for (int idx = t; idx < BLK * E_; idx += 256) {
    int i = idx >> 6, e = idx & 63;
    qsm[i][e] = DN * query[(((size_t)b * T_ + t0 + i) * H_ + h) * E_ + e];
  }
  __syncthreads();
  if (t < BLK) {
    float s = 0.f;
#pragma unroll
    for (int e = 0; e < E_; e++) { float v = qsm[t][e]; s += v * v; }
    qd[t] = 0.5f * s;
  }
  __syncthreads();

  const int m = t;
  for (int g = 0; g < 4; g++) {
    float acc[16];
#pragma unroll
    for (int r = 0; r < 16; r++) acc[r] = 0.f;
    for (int e = 0; e < E_; e++) {
      float pm = projT[e][m];
#pragma unroll
      for (int r = 0; r < 16; r++) acc[r] += qsm[g * 16 + r][e] * pm;
    }
#pragma unroll
    for (int r = 0; r < 16; r++) {
      float v = acc[r];
#pragma unroll
      for (int off = 32; off > 0; off >>= 1) v = fmaxf(v, __shfl_xor(v, off));
      if ((t & 63) == 0) red[t >> 6][r] = v;
    }
    __syncthreads();
    if (t < 16) {
      float v = fmaxf(fmaxf(red[0][t], red[1][t]), fmaxf(red[2][t], red[3][t]));
      smax[t] = v;
      int i = g * 16 + t;
      qls[bh * T_ + t0 + i] = v - qd[i] - HALF_LOG_M;
    }
    __syncthreads();
#pragma unroll
    for (int r = 0; r < 16; r++) {
      float qp = __expf(acc[r] - smax[r]);
      q_prime[((size_t)bh * T_ + t0 + g * 16 + r) * M_ + m] = __float2bfloat16(qp);
    }
    __syncthreads();
  }
}

// kv[m,d] = sum_s k_prime*v ; kp_sum[m] = sum_s k_prime. 8 s-chunks, atomicAdd.
__global__ __launch_bounds__(256) void kv_kernel(
    const float* __restrict__ value, const __hip_bfloat16* __restrict__ k_prime,
    float* __restrict__ kv, float* __restrict__ kpsum) {
  __shared__ float vls[16][E_ + 4];
  const int blk = blockIdx.x;  // B*H*8
  const int chunk = blk & 7;
  const int bh = blk >> 3;
  const int b = bh / H_, h = bh % H_;
  const int s0 = chunk * 256;
  const int t = threadIdx.x;  // = m

  float acc[E_];
#pragma unroll
  for (int d = 0; d < E_; d++) acc[d] = 0.f;
  float ksum = 0.f;

  for (int sc = 0; sc < 16; sc++) {
    __syncthreads();
    {
      int s_l = t >> 4, e4 = (t & 15) * 4;
      const float* vp = value + (((size_t)b * T_ + s0 + sc * 16 + s_l) * H_ + h) * E_ + e4;
      float4 v4 = *reinterpret_cast<const float4*>(vp);
      vls[s_l][e4 + 0] = v4.x; vls[s_l][e4 + 1] = v4.y;
      vls[s_l][e4 + 2] = v4.z; vls[s_l][e4 + 3] = v4.w;
    }
    __syncthreads();
    for (int sl = 0; sl < 16; sl++) {
      float kp = __bfloat162float(k_prime[((size_t)bh * T_ + s0 + sc * 16 + sl) * M_ + t]);
      ksum += kp;
#pragma unroll
      for (int d = 0; d < E_; d++) acc[d] += kp * vls[sl][d];
    }
  }
  float* kvrow = kv + ((size_t)bh * M_ + t) * E_;
#pragma unroll
  for (int d = 0; d < E_; d++) atomicAdd(kvrow + d, acc[d]);
  atomicAdd(kpsum + bh * M_ + t, ksum);
}

// main: per (b,h,n) tile of 64 query rows; 3-window QK + dots_prime + stats + output
__global__ __launch_bounds__(512) void main_kernel(
    const float* __restrict__ query, const float* __restrict__ key,
    const float* __restrict__ value,
    const __hip_bfloat16* __restrict__ q_prime, const __hip_bfloat16* __restrict__ k_prime,
    const float* __restrict__ kv, const float* __restrict__ kpsum,
    const float* __restrict__ qls, const unsigned* __restrict__ skb,
    float* __restrict__ out) {
  __shared__ float qsm[BLK][E_ + 4];                 // 17408 B
  __shared__ float QKs[BLK][3 * BLK + 2];            // 49664 B
  __shared__ __hip_bfloat16 dps[BLK][3 * BLK + 2];   // 24832 B
  __shared__ __align__(16) unsigned char uni[55296]; // kwsT+kpwT | vg
  __shared__ float lnrow[BLK], psrow[BLK];

  float(*kwsT)[72] = reinterpret_cast<float(*)[72]>(uni);                                  // [64][72] f32
  __hip_bfloat16(*kpwT)[72] = reinterpret_cast<__hip_bfloat16(*)[72]>(uni + 18432);        // [256][72]
  __hip_bfloat16(*vg)[72] = reinterpret_cast<__hip_bfloat16(*)[72]>(uni);                  // [192][72]

  const int blk = blockIdx.x;
  const int nb = blk & (NBLK - 1);
  const int bh = blk >> 5;
  const int b = bh / H_, h = bh % H_;
  const int t0 = nb * BLK;
  const int t = threadIdx.x;
  const int i_ = t >> 3;   // 0..63 query row
  const int oct = t & 7;   // 0..7

  const float s_k = unfkey(skb[bh]);

  for (int idx = t; idx < BLK * E_; idx += 512) {
    int i = idx >> 6, e = idx & 63;
    qsm[i][e] = DN * query[(((size_t)b * T_ + t0 + i) * H_ + h) * E_ + e];
  }

  const __hip_bfloat16* qpr = q_prime + ((size_t)bh * T_ + t0 + i_) * M_;

  for (int w = 0; w < 3; w++) {
    const int row = nb + w - 1;
    const bool valid = (row >= 0) && (row < NBLK);
    const int col = (row < 0) ? 0 : ((row > NBLK - 1) ? NBLK - 1 : row);
    __syncthreads();
    if (valid) {
      for (int idx = t; idx < BLK * E_; idx += 512) {
        int j = idx >> 6, e = idx & 63;
        kwsT[e][j] = DN * key[(((size_t)b * T_ + col * BLK + j) * H_ + h) * E_ + e];
      }
      for (int idx = t; idx < BLK * M_; idx += 512) {
        int j = idx >> 8, mm = idx & 255;
        kpwT[mm][j] = k_prime[((size_t)bh * T_ + col * BLK + j) * M_ + mm];
      }
      __syncthreads();
      {  // QK tile (fp32 acc, bf-free: fp32 staged operands)
        float acc[8];
#pragma unroll
        for (int jj = 0; jj < 8; jj++) acc[jj] = 0.f;
        for (int e = 0; e < E_; e++) {
          float qv = qsm[i_][e];
          const float4* kr = reinterpret_cast<const float4*>(&kwsT[e][oct * 8]);
          float4 ka = kr[0], kb = kr[1];
          acc[0] += qv * ka.x; acc[1] += qv * ka.y; acc[2] += qv * ka.z; acc[3] += qv * ka.w;
          acc[4] += qv * kb.x; acc[5] += qv * kb.y; acc[6] += qv * kb.z; acc[7] += qv * kb.w;
        }
#pragma unroll
        for (int jj = 0; jj < 8; jj++) QKs[i_][w * 64 + oct * 8 + jj] = acc[jj];
      }
      {  // dots_prime tile
        float acc[8];
#pragma unroll
        for (int jj = 0; jj < 8; jj++) acc[jj] = 0.f;
        for (int mm = 0; mm < M_; mm++) {
          float qv = __bfloat162float(qpr[mm]);
          const uint4* kr = reinterpret_cast<const uint4*>(&kpwT[mm][oct * 8]);
          uint4 kk = *kr;
          float f0, f1, f2, f3, f4, f5, f6, f7;
          bf2(kk.x, f0, f1); bf2(kk.y, f2, f3); bf2(kk.z, f4, f5); bf2(kk.w, f6, f7);
          acc[0] += qv * f0; acc[1] += qv * f1; acc[2] += qv * f2; acc[3] += qv * f3;
          acc[4] += qv * f4; acc[5] += qv * f5; acc[6] += qv * f6; acc[7] += qv * f7;
        }
#pragma unroll
        for (int jj = 0; jj < 8; jj++)
          dps[i_][w * 64 + oct * 8 + jj] = __float2bfloat16(acc[jj]);
      }
    } else {
      for (int idx = t; idx < BLK * BLK; idx += 512) {
        int i = idx >> 6, j = idx & 63;
        QKs[i][w * 64 + j] = NEGF;
        dps[i][w * 64 + j] = __float2bfloat16(0.f);
      }
    }
  }

  // qp_kp_v into registers (thread owns row i_, dims oct*8..+8)
  float qkv[8];
#pragma unroll
  for (int jj = 0; jj < 8; jj++) qkv[jj] = 0.f;
  {
    const float* kvb = kv + (size_t)bh * M_ * E_ + oct * 8;
    for (int mm = 0; mm < M_; mm++) {
      float qv = __bfloat162float(qpr[mm]);
      const float* kvr = kvb + mm * E_;
#pragma unroll
      for (int jj = 0; jj < 8; jj++) qkv[jj] += qv * kvr[jj];
    }
  }
  __syncthreads();

  // per-row stats
  if (t < BLK) {
    const int i = t;
    float mx = -3.4e38f;
    for (int jw = 0; jw < 192; jw++) mx = fmaxf(mx, QKs[i][jw]);
    float se = 0.f;
    for (int jw = 0; jw < 192; jw++) se += __expf(QKs[i][jw] - mx);
    float lse = mx + __logf(se);
    float dsum = 0.f;
    for (int jw = 0; jw < 192; jw++) dsum += __bfloat162float(dps[i][jw]);
    const __hip_bfloat16* qpr2 = q_prime + ((size_t)bh * T_ + t0 + i) * M_;
    const float* kps = kpsum + bh * M_;
    float qp1 = 0.f;
    for (int mm = 0; mm < M_; mm++) qp1 += __bfloat162float(qpr2[mm]) * kps[mm];
    float pls = qls[bh * T_ + t0 + i] + s_k - HALF_LOG_M;
    float lr = __logf(fmaxf(qp1 - dsum, 1e-24f)) + pls;
    float mab = fmaxf(lse, lr);
    float ln = mab + __logf(__expf(lse - mab) + __expf(lr - mab));
    lnrow[i] = ln;
    psrow[i] = __expf(pls - ln);
  }
  __syncthreads();

  // dots in place: exp(QK - ln) - dp*ps
  for (int idx = t; idx < BLK * 192; idx += 512) {
    int i = idx / 192, jw = idx % 192;
    QKs[i][jw] = __expf(QKs[i][jw] - lnrow[i]) - __bfloat162float(dps[i][jw]) * psrow[i];
  }
  // stage v (3 windows, clipped cols; invalid windows have dots==0 so any v ok)
  for (int idx = t; idx < 3 * BLK * E_; idx += 512) {
    int jw = idx >> 6, e = idx & 63;
    int w = jw >> 6, j = jw & 63;
    int r2 = nb + w - 1;
    int col = (r2 < 0) ? 0 : ((r2 > NBLK - 1) ? NBLK - 1 : r2);
    vg[jw][e] = __float2bfloat16(value[(((size_t)b * T_ + col * BLK + j) * H_ + h) * E_ + e]);
  }
  __syncthreads();

  // output
  {
    float o[8];
    const float ps = psrow[i_];
#pragma unroll
    for (int jj = 0; jj < 8; jj++) o[jj] = qkv[jj] * ps;
    for (int jw = 0; jw < 192; jw++) {
      float dv = QKs[i_][jw];
      const uint4* vr = reinterpret_cast<const uint4*>(&vg[jw][oct * 8]);
      uint4 vv = *vr;
      float f0, f1, f2, f3, f4, f5, f6, f7;
      bf2(vv.x, f0, f1); bf2(vv.y, f2, f3); bf2(vv.z, f4, f5); bf2(vv.w, f6, f7);
      o[0] += dv * f0; o[1] += dv * f1; o[2] += dv * f2; o[3] += dv * f3;
      o[4] += dv * f4; o[5] += dv * f5; o[6] += dv * f6; o[7] += dv * f7;
    }
    float* op = out + (((size_t)b * T_ + t0 + i_) * H_ + h) * E_ + oct * 8;
#pragma unroll
    for (int jj = 0; jj < 8; jj++) op[jj] = o[jj];
  }
}

extern "C" void kernel_launch(void* const* d_in, const int* in_sizes, int n_in,
                              void* d_out, int out_size, void* d_ws, size_t ws_size,
                              hipStream_t stream) {
  const float* query = (const float*)d_in[0];
  const float* key   = (const float*)d_in[1];
  const float* value = (const float*)d_in[2];
  const float* proj  = (const float*)d_in[3];
  float* out = (float*)d_out;

  char* ws = (char*)d_ws;
  unsigned* skb = (unsigned*)(ws + 0);
  float* kpsum = (float*)(ws + 256);
  float* kv = (float*)(ws + 24832);
  float* qls = (float*)(ws + 1597696);
  __hip_bfloat16* q_prime = (__hip_bfloat16*)(ws + 1794304);
  __hip_bfloat16* k_prime = (__hip_bfloat16*)(ws + 26960128);

  init_ws<<<256, 256, 0, stream>>>(skb, kpsum, kv);
  kdash_kernel<false><<<B_ * H_ * NBLK, 256, 0, stream>>>(key, proj, skb, k_prime);
  qdash_kernel<<<B_ * H_ * NBLK, 256, 0, stream>>>(query, proj, qls, q_prime);
  kdash_kernel<true><<<B_ * H_ * NBLK, 256, 0, stream>>>(key, proj, skb, k_prime);
  kv_kernel<<<B_ * H_ * 8, 256, 0, stream>>>(value, k_prime, kv, kpsum);
  main_kernel<<<B_ * H_ * NBLK, 512, 0, stream>>>(query, key, value, q_prime, k_prime,
                                                  kv, kpsum, qls, skb, out);
}

// Round 2
// 212.454 us; speedup vs baseline: 4.9577x; 4.9577x over previous
//
#include <hip/hip_runtime.h>

#define B_ 2
#define T_ 2048
#define H_ 12
#define E_ 64
#define M_ 256
#define BLK 64
#define NBLK 32

typedef _Float16 f16;
typedef f16 f16x2 __attribute__((ext_vector_type(2)));
typedef f16 f16x4 __attribute__((ext_vector_type(4)));
typedef f16 f16x8 __attribute__((ext_vector_type(8)));
typedef float f32x4 __attribute__((ext_vector_type(4)));

#define MFMA16(Av, Bv, Cv) __builtin_amdgcn_mfma_f32_16x16x32_f16(Av, Bv, Cv, 0, 0, 0)

constexpr float DN = 0.35355339059327373f;        // sqrt(temp)
constexpr float HALF_LOG_M = 2.7725887222397811f; // 0.5*ln(256)
constexpr float LN_CQ = 5.545177444479562f;       // ln(256): q_prime scale (denormal guard)
constexpr float LN_CK = 2.772588722239781f;       // ln(16):  k_prime scale
constexpr float DP_SCALE = 0.015625f;             // 2^-6 for dp f16 staging
constexpr float DP_UNSCALE = 64.0f;

// monotonic float<->uint for atomicMax on floats
__device__ __forceinline__ unsigned fkey(float f) {
  unsigned u = __float_as_uint(f);
  return (u & 0x80000000u) ? ~u : (u | 0x80000000u);
}
__device__ __forceinline__ float unfkey(unsigned k) {
  return (k & 0x80000000u) ? __uint_as_float(k & 0x7fffffffu) : __uint_as_float(~k);
}

// ---------------- workspace layout (bytes) ----------------
// 0        : skb      uint[24]                       (256)
// 256      : k_prime  f16 [24][2048][256]  25165824  -> 25166080
// 25166080 : q_prime  f16 [24][2048][256]  25165824  -> 50331904
// 50331904 : qls      f32 [24][2048]         196608  -> 50528512
// 50528512 : kvT      f16 [24][80][256]      983040  -> 51511552  (~51.5 MB, < proven 52.1)

__global__ void init_skb(unsigned* __restrict__ skb) {
  if (threadIdx.x < B_ * H_) skb[threadIdx.x] = 0u;  // below fkey of any float
}

// MODE 0: k_dash pass-A -> global max of k_shift (atomicMax)
// MODE 1: k_dash pass-B -> k_prime = 16*exp(shift - s_k)  (f16)
// MODE 2: q_dash        -> q_prime = 256*exp(qdash - s_q), qls = s_q - qd - HLM - ln256
template <int MODE>
__global__ __launch_bounds__(512) void dash_kernel(
    const float* __restrict__ src, const float* __restrict__ proj,
    unsigned* __restrict__ skb, f16* __restrict__ prime_out,
    float* __restrict__ qls) {
  __shared__ f16 projh[M_][72];   // [m][e]
  __shared__ f16 tsh[BLK][72];    // DN-scaled rows
  __shared__ float td[BLK];       // 0.5*sum(ts^2), fp32
  __shared__ float wred[BLK][2];

  const int blk = blockIdx.x;
  const int nb = blk & (NBLK - 1);
  const int bh = blk >> 5;
  const int b = bh / H_, h = bh % H_;
  const int t0g = nb * BLK;
  const int t = threadIdx.x;
  const int w = t >> 6, l = t & 63, l15 = l & 15, g4 = l >> 4;
  const int rblk = w & 3, cH = w >> 2;
  const int r0 = rblk * 16;

  // stage proj (f32 -> f16), [m][e]
#pragma unroll
  for (int it = 0; it < 8; ++it) {
    int idx = it * 512 + t;
    int m = idx >> 4, e4 = (idx & 15) * 4;
    float4 p4 = *(const float4*)(proj + m * E_ + e4);
    f16x4 h4 = {(f16)p4.x, (f16)p4.y, (f16)p4.z, (f16)p4.w};
    *(f16x4*)&projh[m][e4] = h4;
  }
  // stage tile rows (DN-scaled) + fp32 diag via 16-lane shuffle reduce
#pragma unroll
  for (int it = 0; it < 2; ++it) {
    int idx = it * 512 + t;
    int i = idx >> 4, e4 = (idx & 15) * 4;
    float4 v4 = *(const float4*)(src + (((size_t)b * T_ + t0g + i) * H_ + h) * E_ + e4);
    float a = v4.x * DN, bb = v4.y * DN, c = v4.z * DN, d = v4.w * DN;
    f16x4 h4 = {(f16)a, (f16)bb, (f16)c, (f16)d};
    *(f16x4*)&tsh[i][e4] = h4;
    float p = 0.5f * (a * a + bb * bb + c * c + d * d);
    p += __shfl_xor(p, 1); p += __shfl_xor(p, 2);
    p += __shfl_xor(p, 4); p += __shfl_xor(p, 8);
    if (l15 == 0) td[i] = p;
  }
  __syncthreads();

  // GEMM: [64 x 64] * [64 x 256] -> dash[64][256]; wave: rows rblk*16, cols cH*128
  f32x4 acc[8];
#pragma unroll
  for (int ct = 0; ct < 8; ++ct) acc[ct] = (f32x4){0.f, 0.f, 0.f, 0.f};
#pragma unroll
  for (int kk = 0; kk < 2; ++kk) {
    f16x8 av = *(const f16x8*)&tsh[r0 + l15][kk * 32 + g4 * 8];
#pragma unroll
    for (int ct = 0; ct < 8; ++ct) {
      f16x8 bv = *(const f16x8*)&projh[cH * 128 + ct * 16 + l15][kk * 32 + g4 * 8];
      acc[ct] = MFMA16(av, bv, acc[ct]);
    }
  }

  if (MODE == 0) {
    float td4[4];
#pragma unroll
    for (int r = 0; r < 4; ++r) td4[r] = td[r0 + g4 * 4 + r];
    float lmax = -3.0e38f;
#pragma unroll
    for (int ct = 0; ct < 8; ++ct)
#pragma unroll
      for (int r = 0; r < 4; ++r) lmax = fmaxf(lmax, acc[ct][r] - td4[r]);
#pragma unroll
    for (int off = 32; off; off >>= 1) lmax = fmaxf(lmax, __shfl_xor(lmax, off));
    if (l == 0) wred[w][0] = lmax;
    __syncthreads();
    if (t == 0) {
      float mm = wred[0][0];
#pragma unroll
      for (int ww = 1; ww < 8; ++ww) mm = fmaxf(mm, wred[ww][0]);
      atomicMax(skb + bh, fkey(mm));
    }
  }

  if (MODE == 1) {
    float skv = unfkey(skb[bh]);
    float td4[4];
#pragma unroll
    for (int r = 0; r < 4; ++r) td4[r] = td[r0 + g4 * 4 + r];
#pragma unroll
    for (int ct = 0; ct < 8; ++ct) {
      int col = cH * 128 + ct * 16 + l15;
#pragma unroll
      for (int r = 0; r < 4; ++r) {
        int row = r0 + g4 * 4 + r;
        float kp = __expf(acc[ct][r] - td4[r] - skv + LN_CK);
        prime_out[((size_t)bh * T_ + t0g + row) * M_ + col] = (f16)kp;
      }
    }
  }

  if (MODE == 2) {
    float td4[4];
#pragma unroll
    for (int r = 0; r < 4; ++r) td4[r] = td[r0 + g4 * 4 + r];
    // per-row max across this wave's 128 cols, then merge halves via LDS
#pragma unroll
    for (int r = 0; r < 4; ++r) {
      float v = acc[0][r];
#pragma unroll
      for (int ct = 1; ct < 8; ++ct) v = fmaxf(v, acc[ct][r]);
#pragma unroll
      for (int off = 1; off <= 8; off <<= 1) v = fmaxf(v, __shfl_xor(v, off));
      if (l15 == 0) wred[r0 + g4 * 4 + r][cH] = v;
    }
    __syncthreads();
    float smax[4];
#pragma unroll
    for (int r = 0; r < 4; ++r) {
      int row = r0 + g4 * 4 + r;
      smax[r] = fmaxf(wred[row][0], wred[row][1]);
      if (cH == 0 && l15 == 0)
        qls[(size_t)bh * T_ + t0g + row] = smax[r] - td4[r] - HALF_LOG_M - LN_CQ;
    }
#pragma unroll
    for (int ct = 0; ct < 8; ++ct) {
      int col = cH * 128 + ct * 16 + l15;
#pragma unroll
      for (int r = 0; r < 4; ++r) {
        float qp = __expf(acc[ct][r] - smax[r] + LN_CQ);
        prime_out[((size_t)bh * T_ + t0g + (r0 + g4 * 4 + r)) * M_ + col] = (f16)qp;
      }
    }
  }
}

// kv GEMM per (b,h): kv[m][d] = sum_t kp[t][m]*v[t][d], with ones-column at d=64
// giving kp_sum. Output kvT[d][m] f16 (rows 65..79 zero).
__global__ __launch_bounds__(512) void kv_kernel(
    const float* __restrict__ value, const f16* __restrict__ k_prime,
    f16* __restrict__ kvT) {
  __shared__ f16 kpT[M_][72];  // [m][t-chunk], XOR-unit swizzled
  __shared__ f16 vT[80][72];   // [d][t-chunk], XOR-unit swizzled; row 64 = ones
  const int bh = blockIdx.x;
  const int b = bh / H_, h = bh % H_;
  const int t = threadIdx.x;
  const int w = t >> 6, l = t & 63, l15 = l & 15, g4 = l >> 4;

  for (int idx = t; idx < 16 * 72; idx += 512) {
    int rr = idx / 72, cc = idx % 72;
    vT[64 + rr][cc] = (rr == 0) ? (f16)1.0f : (f16)0.0f;
  }
  f32x4 acc[2][5];
#pragma unroll
  for (int q = 0; q < 2; ++q)
#pragma unroll
    for (int n2 = 0; n2 < 5; ++n2) acc[q][n2] = (f32x4){0.f, 0.f, 0.f, 0.f};

  for (int ch = 0; ch < 32; ++ch) {
    int tbase = ch * 64;
    __syncthreads();  // prev MFMA reads done
    // kp chunk transpose: contiguous global f16x2 reads, b128 swizzled LDS writes
#pragma unroll
    for (int it = 0; it < 2; ++it) {
      int idx = it * 512 + t;
      int m2 = idx & 127, t8 = idx >> 7;
      const f16* gp = k_prime + ((size_t)bh * T_ + tbase + t8 * 8) * M_ + m2 * 2;
      f16x8 a0, a1;
#pragma unroll
      for (int r = 0; r < 8; ++r) {
        f16x2 v2 = *(const f16x2*)(gp + (size_t)r * M_);
        a0[r] = v2[0]; a1[r] = v2[1];
      }
      int m0 = m2 * 2;
      *(f16x8*)&kpT[m0][(t8 ^ ((m0 >> 1) & 7)) * 8] = a0;
      *(f16x8*)&kpT[m0 + 1][(t8 ^ (((m0 + 1) >> 1) & 7)) * 8] = a1;
    }
    // v chunk transpose (d = lane, t8 = wave)
    {
      int d = l, t8 = w;
      const float* gv = value + (((size_t)b * T_ + tbase + t8 * 8) * H_ + h) * E_ + d;
      f16x8 a;
#pragma unroll
      for (int r = 0; r < 8; ++r) a[r] = (f16)gv[(size_t)r * H_ * E_];
      *(f16x8*)&vT[d][(t8 ^ ((d >> 1) & 7)) * 8] = a;
    }
    __syncthreads();
#pragma unroll
    for (int kk = 0; kk < 2; ++kk) {
      int u = kk * 4 + g4;
      f16x8 afr[2];
#pragma unroll
      for (int q = 0; q < 2; ++q) {
        int m = (w * 2 + q) * 16 + l15;
        afr[q] = *(const f16x8*)&kpT[m][(u ^ ((m >> 1) & 7)) * 8];
      }
#pragma unroll
      for (int n2 = 0; n2 < 5; ++n2) {
        int d = n2 * 16 + l15;
        f16x8 bfr = *(const f16x8*)&vT[d][(u ^ ((d >> 1) & 7)) * 8];
#pragma unroll
        for (int q = 0; q < 2; ++q) acc[q][n2] = MFMA16(afr[q], bfr, acc[q][n2]);
      }
    }
  }
#pragma unroll
  for (int q = 0; q < 2; ++q)
#pragma unroll
    for (int n2 = 0; n2 < 5; ++n2) {
      int d = n2 * 16 + l15;
      int m = (w * 2 + q) * 16 + g4 * 4;
      f16x4 h4 = {(f16)acc[q][n2][0], (f16)acc[q][n2][1],
                  (f16)acc[q][n2][2], (f16)acc[q][n2][3]};
      *(f16x4*)(kvT + ((size_t)bh * 80 + d) * M_ + m) = h4;
    }
}

// main: flash-style 3-window loop, all matmuls on MFMA.
// wave w: row-block rblk=w&3 (16 rows), col-half cH=w>>2 (32 cols / 32 dims)
__global__ __launch_bounds__(512) void main_kernel(
    const float* __restrict__ query, const float* __restrict__ key,
    const float* __restrict__ value,
    const f16* __restrict__ q_prime, const f16* __restrict__ k_prime,
    const f16* __restrict__ kvT, const float* __restrict__ qls,
    const unsigned* __restrict__ skb, float* __restrict__ out) {
  __shared__ f16 qsh[BLK][72];
  __shared__ f16 ksh[BLK][72];
  __shared__ f16 vTh[BLK][72];   // swizzled transpose
  __shared__ f16 Ph[BLK][72];    // P tile, then dp tile
  __shared__ float m_run[BLK], l_run[BLK];
  __shared__ float dsum2[BLK][2], wmax[BLK][2], psum[BLK][2];
  __shared__ float mnew_s[BLK], scale_s[BLK];
  __shared__ float qp1row[BLK], efac[BLK], psrow[BLK];

  const int blk = blockIdx.x;
  const int nb = blk & (NBLK - 1);
  const int bh = blk >> 5;
  const int b = bh / H_, h = bh % H_;
  const int t0g = nb * BLK;
  const int t = threadIdx.x;
  const int w = t >> 6, l = t & 63, l15 = l & 15, g4 = l >> 4;
  const int rblk = w & 3, cH = w >> 2;
  const int r0 = rblk * 16;
  const float s_k = unfkey(skb[bh]);

  // stage qs (DN-scaled f16)
#pragma unroll
  for (int it = 0; it < 2; ++it) {
    int idx = it * 512 + t;
    int i = idx >> 4, e4 = (idx & 15) * 4;
    float4 v4 = *(const float4*)(query + (((size_t)b * T_ + t0g + i) * H_ + h) * E_ + e4);
    f16x4 h4 = {(f16)(v4.x * DN), (f16)(v4.y * DN), (f16)(v4.z * DN), (f16)(v4.w * DN)};
    *(f16x4*)&qsh[i][e4] = h4;
  }
  if (t < BLK) {
    m_run[t] = -3.0e38f; l_run[t] = 0.f;
    dsum2[t][0] = 0.f; dsum2[t][1] = 0.f;
  }

  // qp_kp GEMM: [64 x 256] * kvT^T -> [64 x 80]; col-block 4 (d=64) = qp_kp_1
  const int nqt = (w < 4) ? 3 : 2;
  f32x4 qkv[3];
  qkv[0] = qkv[1] = qkv[2] = (f32x4){0.f, 0.f, 0.f, 0.f};
  {
    const f16* qpbase = q_prime + ((size_t)bh * T_ + t0g + r0 + l15) * M_;
#pragma unroll
    for (int kk = 0; kk < 8; ++kk) {
      f16x8 av = *(const f16x8*)(qpbase + kk * 32 + g4 * 8);
      for (int q = 0; q < nqt; ++q) {
        int c0 = (q < 2) ? (cH * 32 + q * 16) : 64;
        f16x8 bv = *(const f16x8*)(kvT + ((size_t)bh * 80 + c0 + l15) * M_ + kk * 32 + g4 * 8);
        qkv[q] = MFMA16(av, bv, qkv[q]);
      }
    }
  }
  if (w < 4 && l15 == 0) {
#pragma unroll
    for (int r = 0; r < 4; ++r) qp1row[r0 + g4 * 4 + r] = qkv[2][r];
  }

  f32x4 oacc[2], dpv[2];
  oacc[0] = oacc[1] = dpv[0] = dpv[1] = (f32x4){0.f, 0.f, 0.f, 0.f};

  for (int wi = 0; wi < 3; ++wi) {
    int rowb = nb + wi - 1;
    if (rowb < 0 || rowb >= NBLK) continue;  // block-uniform
    int tk = rowb * BLK;
    __syncthreads();  // b0: prev dpV done before restage
    // stage ks
#pragma unroll
    for (int it = 0; it < 2; ++it) {
      int idx = it * 512 + t;
      int i = idx >> 4, e4 = (idx & 15) * 4;
      float4 v4 = *(const float4*)(key + (((size_t)b * T_ + tk + i) * H_ + h) * E_ + e4);
      f16x4 h4 = {(f16)(v4.x * DN), (f16)(v4.y * DN), (f16)(v4.z * DN), (f16)(v4.w * DN)};
      *(f16x4*)&ksh[i][e4] = h4;
    }
    // stage vT (transpose-read from global, swizzled b128 writes)
    {
      int d = l, t8 = w;
      const float* gv = value + (((size_t)b * T_ + tk + t8 * 8) * H_ + h) * E_ + d;
      f16x8 a;
#pragma unroll
      for (int r = 0; r < 8; ++r) a[r] = (f16)gv[(size_t)r * H_ * E_];
      *(f16x8*)&vTh[d][(t8 ^ ((d >> 1) & 7)) * 8] = a;
    }
    __syncthreads();  // b1
    // QK (already temp-scaled via DN*DN)
    f32x4 sacc[2];
    sacc[0] = sacc[1] = (f32x4){0.f, 0.f, 0.f, 0.f};
#pragma unroll
    for (int kk = 0; kk < 2; ++kk) {
      f16x8 av = *(const f16x8*)&qsh[r0 + l15][kk * 32 + g4 * 8];
#pragma unroll
      for (int q = 0; q < 2; ++q) {
        f16x8 bv = *(const f16x8*)&ksh[cH * 32 + q * 16 + l15][kk * 32 + g4 * 8];
        sacc[q] = MFMA16(av, bv, sacc[q]);
      }
    }
#pragma unroll
    for (int r = 0; r < 4; ++r) {
      float v = fmaxf(sacc[0][r], sacc[1][r]);
#pragma unroll
      for (int off = 1; off <= 8; off <<= 1) v = fmaxf(v, __shfl_xor(v, off));
      if (l15 == 0) wmax[r0 + g4 * 4 + r][cH] = v;
    }
    __syncthreads();  // b2
    if (t < BLK) {
      float mo = m_run[t];
      float mn = fmaxf(mo, fmaxf(wmax[t][0], wmax[t][1]));
      m_run[t] = mn; mnew_s[t] = mn;
      scale_s[t] = __expf(mo - mn);
    }
    __syncthreads();  // b3
    {
      float mn4[4], sc4[4];
#pragma unroll
      for (int r = 0; r < 4; ++r) {
        int row = r0 + g4 * 4 + r;
        mn4[r] = mnew_s[row]; sc4[r] = scale_s[row];
      }
#pragma unroll
      for (int r = 0; r < 4; ++r) {
        float p0 = __expf(sacc[0][r] - mn4[r]);
        float p1 = __expf(sacc[1][r] - mn4[r]);
        int row = r0 + g4 * 4 + r;
        Ph[row][cH * 32 + l15] = (f16)p0;
        Ph[row][cH * 32 + 16 + l15] = (f16)p1;
        oacc[0][r] *= sc4[r]; oacc[1][r] *= sc4[r];
        float s = p0 + p1;
#pragma unroll
        for (int off = 1; off <= 8; off <<= 1) s += __shfl_xor(s, off);
        if (l15 == 0) psum[row][cH] = s;
      }
    }
    __syncthreads();  // b4: P complete
    if (t < BLK) l_run[t] = l_run[t] * scale_s[t] + psum[t][0] + psum[t][1];
    // PV
#pragma unroll
    for (int kk = 0; kk < 2; ++kk) {
      int u = kk * 4 + g4;
      f16x8 av = *(const f16x8*)&Ph[r0 + l15][kk * 32 + g4 * 8];
#pragma unroll
      for (int q = 0; q < 2; ++q) {
        int d = cH * 32 + q * 16 + l15;
        f16x8 bv = *(const f16x8*)&vTh[d][(u ^ ((d >> 1) & 7)) * 8];
        oacc[q] = MFMA16(av, bv, oacc[q]);
      }
    }
    // dp GEMM (operands straight from L2-resident f16 workspace)
    f32x4 dacc[2];
    dacc[0] = dacc[1] = (f32x4){0.f, 0.f, 0.f, 0.f};
    {
      const f16* qpbase = q_prime + ((size_t)bh * T_ + t0g + r0 + l15) * M_;
      const f16* kpbase = k_prime + ((size_t)bh * T_ + tk) * M_;
#pragma unroll
      for (int kk = 0; kk < 8; ++kk) {
        f16x8 av = *(const f16x8*)(qpbase + kk * 32 + g4 * 8);
#pragma unroll
        for (int q = 0; q < 2; ++q) {
          f16x8 bv = *(const f16x8*)(kpbase + (size_t)(cH * 32 + q * 16 + l15) * M_ + kk * 32 + g4 * 8);
          dacc[q] = MFMA16(av, bv, dacc[q]);
        }
      }
    }
#pragma unroll
    for (int r = 0; r < 4; ++r) {
      float s = dacc[0][r] + dacc[1][r];
#pragma unroll
      for (int off = 1; off <= 8; off <<= 1) s += __shfl_xor(s, off);
      if (l15 == 0) dsum2[r0 + g4 * 4 + r][cH] += s;
    }
    __syncthreads();  // b5: PV done reading Ph
#pragma unroll
    for (int r = 0; r < 4; ++r) {
      int row = r0 + g4 * 4 + r;
      Ph[row][cH * 32 + l15] = (f16)(dacc[0][r] * DP_SCALE);
      Ph[row][cH * 32 + 16 + l15] = (f16)(dacc[1][r] * DP_SCALE);
    }
    __syncthreads();  // b6: dp tile ready
    // dpV
#pragma unroll
    for (int kk = 0; kk < 2; ++kk) {
      int u = kk * 4 + g4;
      f16x8 av = *(const f16x8*)&Ph[r0 + l15][kk * 32 + g4 * 8];
#pragma unroll
      for (int q = 0; q < 2; ++q) {
        int d = cH * 32 + q * 16 + l15;
        f16x8 bv = *(const f16x8*)&vTh[d][(u ^ ((d >> 1) & 7)) * 8];
        dpv[q] = MFMA16(av, bv, dpv[q]);
      }
    }
  }
  __syncthreads();
  if (t < BLK) {
    float lse = m_run[t] + __logf(l_run[t]);
    float dsum = dsum2[t][0] + dsum2[t][1];
    float pls = qls[(size_t)bh * T_ + t0g + t] + s_k - HALF_LOG_M - LN_CK;
    float lr = __logf(fmaxf(qp1row[t] - dsum, 1e-24f)) + pls;
    float mm = fmaxf(lse, lr);
    float ln = mm + __logf(__expf(lse - mm) + __expf(lr - mm));
    efac[t] = __expf(m_run[t] - ln);
    psrow[t] = __expf(pls - ln);
  }
  __syncthreads();
#pragma unroll
  for (int q = 0; q < 2; ++q) {
    int d = cH * 32 + q * 16 + l15;
#pragma unroll
    for (int r = 0; r < 4; ++r) {
      int row = r0 + g4 * 4 + r;
      float val = oacc[q][r] * efac[row] +
                  psrow[row] * (qkv[q][r] - dpv[q][r] * DP_UNSCALE);
      out[(((size_t)b * T_ + t0g + row) * H_ + h) * E_ + d] = val;
    }
  }
}

extern "C" void kernel_launch(void* const* d_in, const int* in_sizes, int n_in,
                              void* d_out, int out_size, void* d_ws, size_t ws_size,
                              hipStream_t stream) {
  const float* query = (const float*)d_in[0];
  const float* key   = (const float*)d_in[1];
  const float* value = (const float*)d_in[2];
  const float* proj  = (const float*)d_in[3];
  float* out = (float*)d_out;

  char* ws = (char*)d_ws;
  unsigned* skb = (unsigned*)ws;
  f16* k_prime = (f16*)(ws + 256);
  f16* q_prime = (f16*)(ws + 25166080);
  float* qls   = (float*)(ws + 50331904);
  f16* kvT     = (f16*)(ws + 50528512);

  init_skb<<<1, 64, 0, stream>>>(skb);
  dash_kernel<0><<<B_ * H_ * NBLK, 512, 0, stream>>>(key, proj, skb, nullptr, nullptr);
  dash_kernel<2><<<B_ * H_ * NBLK, 512, 0, stream>>>(query, proj, skb, q_prime, qls);
  dash_kernel<1><<<B_ * H_ * NBLK, 512, 0, stream>>>(key, proj, skb, k_prime, nullptr);
  kv_kernel<<<B_ * H_, 512, 0, stream>>>(value, k_prime, kvT);
  main_kernel<<<B_ * H_ * NBLK, 512, 0, stream>>>(query, key, value, q_prime, k_prime,
                                                  kvT, qls, skb, out);
}